// Round 1
// baseline (2794.906 us; speedup 1.0000x reference)
//
#include <hip/hip_runtime.h>
#include <math.h>

// SSIM fused kernel: separable 11x11 gaussian depthwise conv of
// {x1, x2, x1^2, x2^2, x1*x2}, SSIM map, global mean -> scalar.
// Layout: NCHW (16,3,512,512) fp32. VALID conv -> 502x502 per plane.

#define W 512
#define H 512
#define OW 502
#define OH 502
#define TR 14                 // output rows per tile (register accumulators = 5*TR)
#define ROWS (TR + 10)        // input rows needed per tile
#define NTILES 36             // ceil(502/14)
#define NPLANES 48            // 16*3
#define NHALF 2               // column halves of 256
#define NBLOCKS (NPLANES * NTILES * NHALF)   // 3456
#define NTOTAL 12096192.0     // 16*3*502*502

struct GaussW { float g[11]; };

__global__ __launch_bounds__(256, 4)
void ssim_main(const float* __restrict__ img1, const float* __restrict__ img2,
               double* __restrict__ partials, GaussW gw)
{
    __shared__ float2 sbuf[272];   // staged row: (x1,x2) interleaved, 256+10 halo
    __shared__ float red[4];

    const int tid  = threadIdx.x;
    const int bid  = blockIdx.x;
    const int half = bid & 1;
    const int tile = (bid >> 1) % NTILES;
    const int plane = bid / (NTILES * NHALF);

    const int c0 = half * 256;
    const int r0 = tile * TR;
    const size_t pbase = (size_t)plane * (W * H);
    const float* __restrict__ p1 = img1 + pbase;
    const float* __restrict__ p2 = img2 + pbase;

    // accumulators: vertical gaussian over horizontal sums, all static-indexed
    float acc1[TR], acc2[TR], acc11[TR], acc22[TR], acc12[TR];
#pragma unroll
    for (int i = 0; i < TR; ++i) {
        acc1[i] = 0.f; acc2[i] = 0.f; acc11[i] = 0.f; acc22[i] = 0.f; acc12[i] = 0.f;
    }

    const int col_main = min(c0 + tid, W - 1);
    const int col_halo = min(c0 + 256 + tid, W - 1);   // used by tid<10 only

    // prefetch row 0
    int row = min(r0, H - 1);
    float a0 = p1[(size_t)row * W + col_main];
    float b0 = p2[(size_t)row * W + col_main];
    float a1 = 0.f, b1 = 0.f;
    if (tid < 10) {
        a1 = p1[(size_t)row * W + col_halo];
        b1 = p2[(size_t)row * W + col_halo];
    }

#pragma unroll
    for (int ir = 0; ir < ROWS; ++ir) {
        __syncthreads();                       // previous row fully consumed
        sbuf[tid] = make_float2(a0, b0);
        if (tid < 10) sbuf[256 + tid] = make_float2(a1, b1);
        // prefetch next row (overlaps with compute below)
        if (ir + 1 < ROWS) {
            int nrow = min(r0 + ir + 1, H - 1);
            a0 = p1[(size_t)nrow * W + col_main];
            b0 = p2[(size_t)nrow * W + col_main];
            if (tid < 10) {
                a1 = p1[(size_t)nrow * W + col_halo];
                b1 = p2[(size_t)nrow * W + col_halo];
            }
        }
        __syncthreads();                       // staging visible

        // horizontal 11-tap: 7 VALU per tap
        float h1 = 0.f, h2 = 0.f, h11 = 0.f, h22 = 0.f, h12 = 0.f;
#pragma unroll
        for (int k = 0; k < 11; ++k) {
            float2 v = sbuf[tid + k];
            float wk = gw.g[k];
            float wa = wk * v.x;
            float wb = wk * v.y;
            h1 += wa;
            h2 += wb;
            h11 = fmaf(wa, v.x, h11);
            h22 = fmaf(wb, v.y, h22);
            h12 = fmaf(wa, v.y, h12);
        }

        // vertical accumulate: row ir contributes to output rows or in [ir-10, ir]
#pragma unroll
        for (int or_ = 0; or_ < TR; ++or_) {
            constexpr int dummy = 0; (void)dummy;
            const int k = ir - or_;            // compile-time (both loops unrolled)
            if (k >= 0 && k <= 10) {
                float wk = gw.g[k];
                acc1[or_]  = fmaf(wk, h1,  acc1[or_]);
                acc2[or_]  = fmaf(wk, h2,  acc2[or_]);
                acc11[or_] = fmaf(wk, h11, acc11[or_]);
                acc22[or_] = fmaf(wk, h22, acc22[or_]);
                acc12[or_] = fmaf(wk, h12, acc12[or_]);
            }
        }
    }

    // SSIM map + per-thread partial sum over valid pixels
    float sum = 0.f;
    const int ocol = c0 + tid;
    const bool colok = (ocol < OW);
    const float C1 = 4.0e-4f;    // (0.01*2)^2
    const float C2 = 3.6e-3f;    // (0.03*2)^2
#pragma unroll
    for (int or_ = 0; or_ < TR; ++or_) {
        const int orow = r0 + or_;
        if (colok && orow < OH) {
            float mu1 = acc1[or_], mu2 = acc2[or_];
            float mu1s = mu1 * mu1;
            float mu2s = mu2 * mu2;
            float mu12 = mu1 * mu2;
            float s11 = acc11[or_] - mu1s;
            float s22 = acc22[or_] - mu2s;
            float s12 = acc12[or_] - mu12;
            float num = (2.f * mu12 + C1) * (2.f * s12 + C2);
            float den = (mu1s + mu2s + C1) * (s11 + s22 + C2);
            sum += num / den;
        }
    }

    // block reduction: wave shfl-reduce (64 lanes) -> 4 partials -> thread 0
#pragma unroll
    for (int off = 32; off > 0; off >>= 1)
        sum += __shfl_down(sum, off, 64);
    if ((tid & 63) == 0) red[tid >> 6] = sum;
    __syncthreads();
    if (tid == 0)
        partials[bid] = (double)(red[0] + red[1] + red[2] + red[3]);
}

__global__ void ssim_final(const double* __restrict__ partials, float* __restrict__ out)
{
    __shared__ double sd[256];
    const int tid = threadIdx.x;
    double s = 0.0;
    for (int i = tid; i < NBLOCKS; i += 256) s += partials[i];
    sd[tid] = s;
    __syncthreads();
    for (int off = 128; off > 0; off >>= 1) {
        if (tid < off) sd[tid] += sd[tid + off];
        __syncthreads();
    }
    if (tid == 0) out[0] = 1.0f - (float)(sd[0] / NTOTAL);
}

extern "C" void kernel_launch(void* const* d_in, const int* in_sizes, int n_in,
                              void* d_out, int out_size, void* d_ws, size_t ws_size,
                              hipStream_t stream)
{
    const float* img1 = (const float*)d_in[0];
    const float* img2 = (const float*)d_in[1];
    float* out = (float*)d_out;
    double* partials = (double*)d_ws;   // NBLOCKS doubles = 27648 B

    // gaussian weights, matching numpy float32: exp(-(i-5)^2 / (2*1.5^2)), normalized
    GaussW gw;
    float tmp[11];
    float s = 0.f;
    for (int i = 0; i < 11; ++i) {
        float d = (float)(i - 5);
        tmp[i] = expf(-(d * d) / 4.5f);
        s += tmp[i];
    }
    for (int i = 0; i < 11; ++i) gw.g[i] = tmp[i] / s;

    ssim_main<<<NBLOCKS, 256, 0, stream>>>(img1, img2, partials, gw);
    ssim_final<<<1, 256, 0, stream>>>(partials, out);
}

// Round 2
// 66.904 us; speedup vs baseline: 41.7747x; 41.7747x over previous
//
#include <hip/hip_runtime.h>
#include <math.h>

// Fused SSIM: separable 11x11 gaussian depthwise conv of {x1,x2,x1^2,x2^2,x1*x2},
// SSIM map, global mean -> scalar. NCHW (16,3,512,512) fp32, VALID -> 502x502.
//
// Structure: block = 256 threads = 256 columns (one half of the image width),
// sweeping a strip of 63 output rows. Horizontal 11-tap from an LDS-staged row
// (ping-pong, 1 barrier/row); vertical 11-tap via a rotating 11-slot register
// window whose indices are all parse-time constants (macro-literal P/D) so the
// accumulators are guaranteed VGPRs (R0 failure: SROA left acc[] in scratch ->
// 3.9 GB of spill traffic).

#define W 512
#define H 512
#define OWID 502            // output rows/cols (512-11+1)
#define NS 8                // row strips
#define SH 63               // output rows per strip (ceil(502/8))
#define NPLANES 48          // 16*3
#define NBLOCKS (NPLANES * 2 * NS)   // 768
#define NTOTAL 12096192.0   // 48*502*502

// gaussian(sigma=1.5, ws=11), normalized; compile-time constants.
#define G0 0.00102838f
#define G1 0.00759860f
#define G2 0.03600090f
#define G3 0.10936100f
#define G4 0.21300540f
#define G5 0.26601170f

__device__ __constant__ const float Gc[11] = {G0,G1,G2,G3,G4,G5,G4,G3,G2,G1,G0};

// vertical tap: slot index is a constant expression (P,D are literals)
#define VTAP(P,D) { \
    constexpr int s_ = (((P) - (D)) % 11 + 11) % 11; \
    constexpr float wv_ = ((D)==0||(D)==10) ? G0 : ((D)==1||(D)==9) ? G1 : \
                          ((D)==2||(D)==8)  ? G2 : ((D)==3||(D)==7) ? G3 : \
                          ((D)==4||(D)==6)  ? G4 : G5; \
    acc1[s_]  = fmaf(wv_, h1,  acc1[s_]); \
    acc2[s_]  = fmaf(wv_, h2,  acc2[s_]); \
    acc11[s_] = fmaf(wv_, h11, acc11[s_]); \
    acc22[s_] = fmaf(wv_, h22, acc22[s_]); \
    acc12[s_] = fmaf(wv_, h12, acc12[s_]); }

#define PHASE(P) { \
    float2* sb_ = sbuf[ir & 1]; \
    sb_[tid] = make_float2(a0, b0); \
    if (tid < 10) sb_[256 + tid] = make_float2(a1, b1); \
    __syncthreads(); \
    { const size_t nro_ = (size_t)min(ir + 1, H - 1) * W; \
      a0 = p1[nro_ + col_main]; b0 = p2[nro_ + col_main]; \
      if (tid < 10) { a1 = p1[nro_ + col_halo]; b1 = p2[nro_ + col_halo]; } } \
    float h1 = 0.f, h2 = 0.f, h11 = 0.f, h22 = 0.f, h12 = 0.f; \
    _Pragma("unroll") \
    for (int k = 0; k < 11; ++k) { \
        float2 v_ = sb_[tid + k]; \
        float wk_ = Gc[k]; \
        float wa_ = wk_ * v_.x, wb_ = wk_ * v_.y; \
        h1 += wa_; h2 += wb_; \
        h11 = fmaf(wa_, v_.x, h11); \
        h22 = fmaf(wb_, v_.y, h22); \
        h12 = fmaf(wa_, v_.y, h12); } \
    VTAP(P,0) VTAP(P,1) VTAP(P,2) VTAP(P,3) VTAP(P,4) VTAP(P,5) \
    VTAP(P,6) VTAP(P,7) VTAP(P,8) VTAP(P,9) VTAP(P,10) \
    { constexpr int cs_ = ((P) + 1) % 11; \
      const int orow_ = ir - 10; \
      if (colok && orow_ >= r0 && orow_ < r1) { \
          float mu1_ = acc1[cs_], mu2_ = acc2[cs_]; \
          float m1s_ = mu1_ * mu1_, m2s_ = mu2_ * mu2_, m12_ = mu1_ * mu2_; \
          float s11_ = acc11[cs_] - m1s_; \
          float s22_ = acc22[cs_] - m2s_; \
          float s12_ = acc12[cs_] - m12_; \
          float num_ = (2.f * m12_ + C1) * (2.f * s12_ + C2); \
          float den_ = (m1s_ + m2s_ + C1) * (s11_ + s22_ + C2); \
          sum += num_ / den_; } \
      acc1[cs_] = 0.f; acc2[cs_] = 0.f; acc11[cs_] = 0.f; \
      acc22[cs_] = 0.f; acc12[cs_] = 0.f; } \
    ++ir; }

__global__ __launch_bounds__(256, 4)
void ssim_main(const float* __restrict__ img1, const float* __restrict__ img2,
               double* __restrict__ partials)
{
    __shared__ float2 sbuf[2][272];   // ping-pong staged row (x1,x2), 256+10 halo
    __shared__ float red[4];

    const int tid   = threadIdx.x;
    const int bid   = blockIdx.x;
    const int half  = bid & 1;
    const int strip = (bid >> 1) % NS;
    const int plane = bid / (2 * NS);

    const int c0 = half * 256;
    const int r0 = strip * SH;
    const int nrows = min(SH, OWID - r0);
    const int r1 = r0 + nrows;
    const int ngroups = (nrows + 20) / 11;   // ceil((nrows+10)/11)

    const size_t pbase = (size_t)plane * (W * H);
    const float* __restrict__ p1 = img1 + pbase;
    const float* __restrict__ p2 = img2 + pbase;

    const int col_main = c0 + tid;                       // < 512 always
    const int col_halo = min(c0 + 256 + tid, W - 1);     // used by tid<10 only
    const bool colok = (c0 + tid) < OWID;

    const float C1 = 4.0e-4f;    // (0.01*2)^2
    const float C2 = 3.6e-3f;    // (0.03*2)^2

    // rotating 11-slot accumulators (all indices parse-time constants)
    float acc1[11], acc2[11], acc11[11], acc22[11], acc12[11];
#pragma unroll
    for (int i = 0; i < 11; ++i) {
        acc1[i] = 0.f; acc2[i] = 0.f; acc11[i] = 0.f; acc22[i] = 0.f; acc12[i] = 0.f;
    }

    float sum = 0.f;
    int ir = r0;

    // prefetch first row
    {
        const size_t ro = (size_t)ir * W;
        float a0x = p1[ro + col_main];
        (void)a0x;
    }
    float a0, b0, a1 = 0.f, b1 = 0.f;
    {
        const size_t ro = (size_t)ir * W;
        a0 = p1[ro + col_main];
        b0 = p2[ro + col_main];
        if (tid < 10) { a1 = p1[ro + col_halo]; b1 = p2[ro + col_halo]; }
    }

    for (int g = 0; g < ngroups; ++g) {
        PHASE(0) PHASE(1) PHASE(2) PHASE(3) PHASE(4) PHASE(5)
        PHASE(6) PHASE(7) PHASE(8) PHASE(9) PHASE(10)
    }

    // block reduction: per-wave shfl tree -> 4 partials -> thread 0
#pragma unroll
    for (int off = 32; off > 0; off >>= 1)
        sum += __shfl_down(sum, off, 64);
    if ((tid & 63) == 0) red[tid >> 6] = sum;
    __syncthreads();
    if (tid == 0)
        partials[bid] = (double)(red[0] + red[1] + red[2] + red[3]);
}

__global__ void ssim_final(const double* __restrict__ partials, float* __restrict__ out)
{
    __shared__ double sd[256];
    const int tid = threadIdx.x;
    double s = 0.0;
    for (int i = tid; i < NBLOCKS; i += 256) s += partials[i];
    sd[tid] = s;
    __syncthreads();
    for (int off = 128; off > 0; off >>= 1) {
        if (tid < off) sd[tid] += sd[tid + off];
        __syncthreads();
    }
    if (tid == 0) out[0] = 1.0f - (float)(sd[0] / NTOTAL);
}

extern "C" void kernel_launch(void* const* d_in, const int* in_sizes, int n_in,
                              void* d_out, int out_size, void* d_ws, size_t ws_size,
                              hipStream_t stream)
{
    const float* img1 = (const float*)d_in[0];
    const float* img2 = (const float*)d_in[1];
    float* out = (float*)d_out;
    double* partials = (double*)d_ws;   // NBLOCKS doubles = 6144 B

    ssim_main<<<NBLOCKS, 256, 0, stream>>>(img1, img2, partials);
    ssim_final<<<1, 256, 0, stream>>>(partials, out);
}